// Round 5
// baseline (681.933 us; speedup 1.0000x reference)
//
#include <hip/hip_runtime.h>

typedef unsigned short u16;
typedef float f32x4 __attribute__((ext_vector_type(4)));
typedef short bf16x8 __attribute__((ext_vector_type(8)));

#define GLOAD16(gp, lp) __builtin_amdgcn_global_load_lds( \
    (const __attribute__((address_space(1))) void*)(gp),  \
    (__attribute__((address_space(3))) void*)(lp), 16, 0, 0)

__device__ __forceinline__ float bf2f(u16 u) {
  union { unsigned int i; float f; } v; v.i = ((unsigned int)u) << 16; return v.f;
}
__device__ __forceinline__ u16 f2bf(float f) {
  unsigned int u = __float_as_uint(f);
  u += 0x7FFFu + ((u >> 16) & 1u);
  return (u16)(u >> 16);
}

// ---------------- trig table: trig[pos*64+i] = (cos, sin)(pos * 10000^(-i/64)) ---
__global__ void trig_kernel(float2* __restrict__ trig) {
  int idx = blockIdx.x * 256 + threadIdx.x;   // 131072 = 2048*64
  int pos = idx >> 6, i = idx & 63;
  double invf = pow(10000.0, -(double)i / 64.0);
  float ang = (float)pos * (float)invf;
  trig[idx] = make_float2(cosf(ang), sinf(ang));
}

// ---------------- x f32 -> bf16 -----------------------------------------------
__global__ void convert_x(const float* __restrict__ src, u16* __restrict__ dst) {
  size_t idx = (size_t)blockIdx.x * 256 + threadIdx.x;  // 2,097,152
  float4 v = *(const float4*)&src[idx * 4];
  *(ushort4*)&dst[idx * 4] = make_ushort4(f2bf(v.x), f2bf(v.y), f2bf(v.z), f2bf(v.w));
}

// ---------------- W [k][n] f32 -> Wt [n][k] bf16 (128x128 LDS tiles) ----------
__global__ void transpose_w(const float* __restrict__ src, u16* __restrict__ dst) {
  __shared__ u16 tile[128][129];
  int k0 = blockIdx.x * 128, n0 = blockIdx.y * 128;
  int t = threadIdx.x;
  for (int j = 0; j < 16; ++j) {
    int flat = j * 1024 + t * 4;
    int r = flat >> 7, cl = flat & 127;
    float4 v = *(const float4*)&src[(size_t)(k0 + r) * 2048 + n0 + cl];
    tile[r][cl] = f2bf(v.x); tile[r][cl+1] = f2bf(v.y);
    tile[r][cl+2] = f2bf(v.z); tile[r][cl+3] = f2bf(v.w);
  }
  __syncthreads();
  for (int j = 0; j < 16; ++j) {
    int flat = j * 1024 + t * 4;
    int r = flat >> 7, cl = flat & 127;
    ushort4 o = make_ushort4(tile[cl][r], tile[cl+1][r], tile[cl+2][r], tile[cl+3][r]);
    *(ushort4*)&dst[(size_t)(n0 + r) * 2048 + k0 + cl] = o;
  }
}

// ---------------- GEMM: C[M,N] = A[M,K] * Bt[N,K]^T, 128x128 tile, BK=32 ------
// frag-ordered LDS: unit R (1KB) holds, in lane order l, 16B of
// A[m0 + R*16 + (l&15)][k0 + (l>>4)*8 .. +8]  -> ds_read_b128 is a contiguous
// 1KB wave read (conflict-free); global_load_lds dest stays linear.
template<int WF32>
__global__ void __launch_bounds__(256) gemm_bt(
    const u16* __restrict__ A, const u16* __restrict__ Bt,
    void* __restrict__ Cp, int ldc, int nbx, int kt_iters, int lda, int ldb)
{
  __shared__ __align__(16) u16 lds_a[4096];
  __shared__ __align__(16) u16 lds_b[4096];
  int nb = gridDim.x;
  int per = nb >> 3;                       // grid % 8 == 0 (XCD swizzle)
  int bid = blockIdx.x;
  int sw = (bid & 7) * per + (bid >> 3);
  int bm = sw / nbx, bn = sw % nbx;
  int tid = threadIdx.x, w = tid >> 6, lane = tid & 63;
  int wy = w >> 1, wx = w & 1, g = lane >> 4, c16 = lane & 15;

  const u16* ga0 = A  + (size_t)(bm * 128 + (2*w+0) * 16 + c16) * lda + g * 8;
  const u16* ga1 = A  + (size_t)(bm * 128 + (2*w+1) * 16 + c16) * lda + g * 8;
  const u16* gb0 = Bt + (size_t)(bn * 128 + (2*w+0) * 16 + c16) * ldb + g * 8;
  const u16* gb1 = Bt + (size_t)(bn * 128 + (2*w+1) * 16 + c16) * ldb + g * 8;
  u16* la0 = &lds_a[(2*w+0) * 512]; u16* la1 = &lds_a[(2*w+1) * 512];
  u16* lb0 = &lds_b[(2*w+0) * 512]; u16* lb1 = &lds_b[(2*w+1) * 512];

  f32x4 acc[4][4];
  const f32x4 vzero = {0.f, 0.f, 0.f, 0.f};
  #pragma unroll
  for (int i = 0; i < 4; ++i)
    #pragma unroll
    for (int j = 0; j < 4; ++j) acc[i][j] = vzero;

  for (int kt = 0; kt < kt_iters; ++kt) {
    int ko = kt * 32;
    __syncthreads();
    GLOAD16(ga0 + ko, la0); GLOAD16(ga1 + ko, la1);
    GLOAD16(gb0 + ko, lb0); GLOAD16(gb1 + ko, lb1);
    __syncthreads();
    bf16x8 af[4], bfv[4];
    #pragma unroll
    for (int f = 0; f < 4; ++f) af[f]  = *(const bf16x8*)&lds_a[(wy*4 + f) * 512 + lane * 8];
    #pragma unroll
    for (int f = 0; f < 4; ++f) bfv[f] = *(const bf16x8*)&lds_b[(wx*4 + f) * 512 + lane * 8];
    #pragma unroll
    for (int i = 0; i < 4; ++i)
      #pragma unroll
      for (int j = 0; j < 4; ++j)
        acc[i][j] = __builtin_amdgcn_mfma_f32_16x16x32_bf16(af[i], bfv[j], acc[i][j], 0, 0, 0);
  }

  #pragma unroll
  for (int i = 0; i < 4; ++i)
    #pragma unroll
    for (int j = 0; j < 4; ++j)
      #pragma unroll
      for (int r = 0; r < 4; ++r) {
        size_t row = (size_t)bm * 128 + wy * 64 + i * 16 + 4 * g + r;
        size_t col = (size_t)bn * 128 + wx * 64 + j * 16 + c16;
        if (WF32) ((float*)Cp)[row * ldc + col] = acc[i][j][r];
        else      ((u16*)Cp)[row * ldc + col]   = f2bf(acc[i][j][r]);
      }
}

// ---------------- RoPE on q columns of C1 in place, pre-scaled ----------------
__global__ void rope_q(u16* __restrict__ C1, const float2* __restrict__ trig) {
  int idx = blockIdx.x * 256 + threadIdx.x;   // 4096 rows * 1024 pairs
  int row = idx >> 10;
  int pi = idx & 1023;
  int h = pi >> 6, i = pi & 63;
  int pos = 1024 + (row & 1023);
  float2 cs = trig[pos * 64 + i];
  u16* p = &C1[(size_t)row * 6144 + h * 128 + 2 * i];
  ushort2 xv = *(const ushort2*)p;
  float x0 = bf2f(xv.x), x1 = bf2f(xv.y);
  const float SC = 0.088388347648318447f * 1.4426950408889634f; // 1/sqrt(128)*log2(e)
  float y0 = (x0 * cs.x - x1 * cs.y) * SC;
  float y1 = (x1 * cs.x + x0 * cs.y) * SC;
  *(ushort2*)p = make_ushort2(f2bf(y0), f2bf(y1));
}

// ---------------- K[bh][s][d] bf16, roped, from past_k | C1 k-cols ------------
__global__ void build_k(const float* __restrict__ past_k, const u16* __restrict__ C1,
                        const float2* __restrict__ trig, u16* __restrict__ Kb) {
  int idx = blockIdx.x * 256 + threadIdx.x;   // 64 * 2048 * 64
  int i = idx & 63;
  int s = (idx >> 6) & 2047;
  int bh = idx >> 17;
  int b = bh >> 4, h = bh & 15;
  float x0, x1;
  if (s < 1024) {
    const float* p = &past_k[(size_t)((b * 1024 + s) * 16 + h) * 128 + 2 * i];
    float2 v = *(const float2*)p;
    x0 = v.x; x1 = v.y;
  } else {
    ushort2 v = *(const ushort2*)&C1[(size_t)(b * 1024 + s - 1024) * 6144 + 2048 + h * 128 + 2 * i];
    x0 = bf2f(v.x); x1 = bf2f(v.y);
  }
  float2 cs = trig[s * 64 + i];
  float y0 = x0 * cs.x - x1 * cs.y;
  float y1 = x1 * cs.x + x0 * cs.y;
  *(ushort2*)&Kb[((size_t)bh * 2048 + s) * 128 + 2 * i] = make_ushort2(f2bf(y0), f2bf(y1));
}

// ---------------- Vt[bh][d][s] bf16 from past_v | C1 v-cols (transpose) -------
__global__ void build_vt(const float* __restrict__ past_v, const u16* __restrict__ C1,
                         u16* __restrict__ Vt) {
  __shared__ u16 tile[128][129];
  int bh = blockIdx.x, st = blockIdx.y;
  int b = bh >> 4, h = bh & 15;
  int s0 = st * 128;
  int t = threadIdx.x;
  for (int j = 0; j < 16; ++j) {
    int flat = j * 1024 + t * 4;
    int sl = flat >> 7, dl = flat & 127;
    u16 a, bq, cq, dq;
    if (st < 8) {
      float4 v = *(const float4*)&past_v[(size_t)((b * 1024 + s0 + sl) * 16 + h) * 128 + dl];
      a = f2bf(v.x); bq = f2bf(v.y); cq = f2bf(v.z); dq = f2bf(v.w);
    } else {
      ushort4 v = *(const ushort4*)&C1[(size_t)(b * 1024 + s0 + sl - 1024) * 6144 + 4096 + h * 128 + dl];
      a = v.x; bq = v.y; cq = v.z; dq = v.w;
    }
    tile[sl][dl] = a; tile[sl][dl+1] = bq; tile[sl][dl+2] = cq; tile[sl][dl+3] = dq;
  }
  __syncthreads();
  for (int j = 0; j < 16; ++j) {
    int flat = j * 1024 + t * 4;
    int dl = flat >> 7, sl = flat & 127;
    ushort4 o = make_ushort4(tile[sl][dl], tile[sl+1][dl], tile[sl+2][dl], tile[sl+3][dl]);
    *(ushort4*)&Vt[((size_t)bh * 128 + dl) * 2048 + s0 + sl] = o;
  }
}

// ---------------- flash attention: QBLK=64 (4 waves x 16 rows), KBLK=64 -------
__global__ void __launch_bounds__(256) attn_kernel(
    const u16* __restrict__ Q, const u16* __restrict__ Kb,
    const u16* __restrict__ Vt, u16* __restrict__ Y)
{
  __shared__ __align__(16) u16 ldsK[8192];     // 16 frag units x 1KB
  __shared__ __align__(16) u16 ldsV[8192];
  __shared__ __align__(16) u16 ldsP[4][1024];  // per-wave 16x64 P, XOR-swizzled
  int qt = blockIdx.x, bh = blockIdx.y;
  int b = bh >> 4, h = bh & 15;
  int w = threadIdx.x >> 6, lane = threadIdx.x & 63;
  int g = lane >> 4, c16 = lane & 15;

  bf16x8 qf[4];
  {
    const u16* qp = Q + (size_t)(b * 1024 + qt * 64 + w * 16 + c16) * 6144 + h * 128 + g * 8;
    #pragma unroll
    for (int c = 0; c < 4; ++c) qf[c] = *(const bf16x8*)(qp + c * 32);
  }
  const u16* Kh = Kb + (size_t)bh * 2048 * 128;
  const u16* Vh = Vt + (size_t)bh * 128 * 2048;
  const u16* gk[4]; const u16* gv[4];
  #pragma unroll
  for (int j = 0; j < 4; ++j) {
    int u = w * 4 + j;
    gk[j] = Kh + (size_t)(16 * w + c16) * 128 + j * 32 + g * 8;
    int dt = u >> 1, sc = u & 1;
    gv[j] = Vh + (size_t)(16 * dt + c16) * 2048 + sc * 32 + g * 8;
  }

  const f32x4 vzero = {0.f, 0.f, 0.f, 0.f};
  f32x4 yacc[8];
  #pragma unroll
  for (int dt = 0; dt < 8; ++dt) yacc[dt] = vzero;
  float m_run[4] = {-3e38f, -3e38f, -3e38f, -3e38f};
  float l_run[4] = {0.f, 0.f, 0.f, 0.f};

  int ntiles = 17 + qt;                        // last tile is the diagonal one
  for (int it = 0; it < ntiles; ++it) {
    int s0 = it * 64;
    __syncthreads();
    #pragma unroll
    for (int j = 0; j < 4; ++j) GLOAD16(gk[j] + (size_t)s0 * 128, &ldsK[(w * 4 + j) * 512]);
    #pragma unroll
    for (int j = 0; j < 4; ++j) GLOAD16(gv[j] + s0, &ldsV[(w * 4 + j) * 512]);
    __syncthreads();

    f32x4 sc_[4];
    #pragma unroll
    for (int t = 0; t < 4; ++t) sc_[t] = vzero;
    #pragma unroll
    for (int t = 0; t < 4; ++t)
      #pragma unroll
      for (int c = 0; c < 4; ++c) {
        bf16x8 kbf = *(const bf16x8*)&ldsK[(t * 4 + c) * 512 + lane * 8];
        sc_[t] = __builtin_amdgcn_mfma_f32_16x16x32_bf16(qf[c], kbf, sc_[t], 0, 0, 0);
      }
    if (it == ntiles - 1) {
      #pragma unroll
      for (int t = 0; t < 4; ++t)
        #pragma unroll
        for (int r = 0; r < 4; ++r)
          if (16 * t + c16 > 16 * w + 4 * g + r) sc_[t][r] = -3e38f;
    }

    float tmax[4];
    #pragma unroll
    for (int r = 0; r < 4; ++r)
      tmax[r] = fmaxf(fmaxf(sc_[0][r], sc_[1][r]), fmaxf(sc_[2][r], sc_[3][r]));
    #pragma unroll
    for (int off = 1; off < 16; off <<= 1)
      #pragma unroll
      for (int r = 0; r < 4; ++r) tmax[r] = fmaxf(tmax[r], __shfl_xor(tmax[r], off));

    float m_new[4], alpha[4];
    #pragma unroll
    for (int r = 0; r < 4; ++r) {
      m_new[r] = fmaxf(m_run[r], tmax[r]);
      alpha[r] = exp2f(m_run[r] - m_new[r]);
      m_run[r] = m_new[r];
    }
    float psum[4] = {0.f, 0.f, 0.f, 0.f};
    #pragma unroll
    for (int t = 0; t < 4; ++t)
      #pragma unroll
      for (int r = 0; r < 4; ++r) {
        float p = exp2f(sc_[t][r] - m_new[r]);
        psum[r] += p;
        int row = 4 * g + r, key = 16 * t + c16;
        ldsP[w][row * 64 + (((key >> 3) ^ (row & 7)) << 3) + (key & 7)] = f2bf(p);
      }
    #pragma unroll
    for (int off = 1; off < 16; off <<= 1)
      #pragma unroll
      for (int r = 0; r < 4; ++r) psum[r] += __shfl_xor(psum[r], off);
    #pragma unroll
    for (int r = 0; r < 4; ++r) l_run[r] = l_run[r] * alpha[r] + psum[r];
    #pragma unroll
    for (int dt = 0; dt < 8; ++dt)
      #pragma unroll
      for (int r = 0; r < 4; ++r) yacc[dt][r] *= alpha[r];

    bf16x8 pa[2];
    #pragma unroll
    for (int s2 = 0; s2 < 2; ++s2)
      pa[s2] = *(const bf16x8*)&ldsP[w][c16 * 64 + (((g + 4 * s2) ^ (c16 & 7)) << 3)];

    #pragma unroll
    for (int dt = 0; dt < 8; ++dt)
      #pragma unroll
      for (int s2 = 0; s2 < 2; ++s2) {
        bf16x8 vb = *(const bf16x8*)&ldsV[(dt * 2 + s2) * 512 + lane * 8];
        yacc[dt] = __builtin_amdgcn_mfma_f32_16x16x32_bf16(pa[s2], vb, yacc[dt], 0, 0, 0);
      }
  }

  float linv[4];
  #pragma unroll
  for (int r = 0; r < 4; ++r) linv[r] = 1.0f / l_run[r];
  size_t ybase = (size_t)(b * 1024 + qt * 64 + w * 16) * 2048 + h * 128;
  #pragma unroll
  for (int dt = 0; dt < 8; ++dt)
    #pragma unroll
    for (int r = 0; r < 4; ++r)
      Y[ybase + (size_t)(4 * g + r) * 2048 + dt * 16 + c16] = f2bf(yacc[dt][r] * linv[r]);
}

// ------------------------------------------------------------------------------
extern "C" void kernel_launch(void* const* d_in, const int* in_sizes, int n_in,
                              void* d_out, int out_size, void* d_ws, size_t ws_size,
                              hipStream_t stream) {
  const float* x  = (const float*)d_in[0];
  const float* pk = (const float*)d_in[1];
  const float* pv = (const float*)d_in[2];
  const float* Wq = (const float*)d_in[3];
  const float* Wk = (const float*)d_in[4];
  const float* Wv = (const float*)d_in[5];
  const float* Wo = (const float*)d_in[6];
  float* out = (float*)d_out;
  char* ws = (char*)d_ws;
  size_t off = 0;
  float2* trig = (float2*)(ws + off); off += (size_t)2048 * 64 * 8;
  u16* xbf     = (u16*)(ws + off);    off += (size_t)4096 * 2048 * 2;
  u16* wqkvt   = (u16*)(ws + off);    off += (size_t)6144 * 2048 * 2;
  u16* wot     = (u16*)(ws + off);    off += (size_t)2048 * 2048 * 2;
  u16* c1      = (u16*)(ws + off);    off += (size_t)4096 * 6144 * 2;
  u16* kb      = (u16*)(ws + off);    off += (size_t)64 * 2048 * 128 * 2;
  u16* vt      = (u16*)(ws + off);    off += (size_t)64 * 128 * 2048 * 2;
  u16* yb      = (u16*)(ws + off);    off += (size_t)4096 * 2048 * 2;

  trig_kernel<<<512, 256, 0, stream>>>(trig);
  convert_x<<<8192, 256, 0, stream>>>(x, xbf);
  transpose_w<<<dim3(16, 16), 256, 0, stream>>>(Wq, wqkvt);
  transpose_w<<<dim3(16, 16), 256, 0, stream>>>(Wk, wqkvt + (size_t)2048 * 2048);
  transpose_w<<<dim3(16, 16), 256, 0, stream>>>(Wv, wqkvt + (size_t)2 * 2048 * 2048);
  transpose_w<<<dim3(16, 16), 256, 0, stream>>>(Wo, wot);
  gemm_bt<0><<<1536, 256, 0, stream>>>(xbf, wqkvt, (void*)c1, 6144, 48, 64, 2048, 2048);
  rope_q<<<16384, 256, 0, stream>>>(c1, trig);
  build_k<<<32768, 256, 0, stream>>>(pk, c1, trig, kb);
  build_vt<<<dim3(64, 16), 256, 0, stream>>>(pv, c1, vt);
  attn_kernel<<<dim3(16, 64), 256, 0, stream>>>(c1, kb, vt, yb);
  gemm_bt<1><<<512, 256, 0, stream>>>(yb, wot, (void*)out, 2048, 16, 64, 2048, 2048);
}

// Round 6
// 669.391 us; speedup vs baseline: 1.0187x; 1.0187x over previous
//
#include <hip/hip_runtime.h>

typedef unsigned short u16;
typedef float f32x4 __attribute__((ext_vector_type(4)));
typedef short bf16x8 __attribute__((ext_vector_type(8)));

#define GLOAD16(gp, lp) __builtin_amdgcn_global_load_lds( \
    (const __attribute__((address_space(1))) void*)(gp),  \
    (__attribute__((address_space(3))) void*)(lp), 16, 0, 0)

__device__ __forceinline__ float bf2f(u16 u) {
  union { unsigned int i; float f; } v; v.i = ((unsigned int)u) << 16; return v.f;
}
__device__ __forceinline__ u16 f2bf(float f) {
  unsigned int u = __float_as_uint(f);
  u += 0x7FFFu + ((u >> 16) & 1u);
  return (u16)(u >> 16);
}

// ---------------- trig table: trig[pos*64+i] = (cos, sin)(pos * 10000^(-i/64)) ---
__global__ void trig_kernel(float2* __restrict__ trig) {
  int idx = blockIdx.x * 256 + threadIdx.x;   // 131072 = 2048*64
  int pos = idx >> 6, i = idx & 63;
  double invf = pow(10000.0, -(double)i / 64.0);
  float ang = (float)pos * (float)invf;
  trig[idx] = make_float2(cosf(ang), sinf(ang));
}

// ---------------- x f32 -> bf16 -----------------------------------------------
__global__ void convert_x(const float* __restrict__ src, u16* __restrict__ dst) {
  size_t idx = (size_t)blockIdx.x * 256 + threadIdx.x;  // 2,097,152
  float4 v = *(const float4*)&src[idx * 4];
  *(ushort4*)&dst[idx * 4] = make_ushort4(f2bf(v.x), f2bf(v.y), f2bf(v.z), f2bf(v.w));
}

// ---------------- W [k][n] f32 -> Wt [n][k] bf16 (128x128 LDS tiles) ----------
__global__ void transpose_w(const float* __restrict__ src, u16* __restrict__ dst) {
  __shared__ u16 tile[128][129];
  int k0 = blockIdx.x * 128, n0 = blockIdx.y * 128;
  int t = threadIdx.x;
  for (int j = 0; j < 16; ++j) {
    int flat = j * 1024 + t * 4;
    int r = flat >> 7, cl = flat & 127;
    float4 v = *(const float4*)&src[(size_t)(k0 + r) * 2048 + n0 + cl];
    tile[r][cl] = f2bf(v.x); tile[r][cl+1] = f2bf(v.y);
    tile[r][cl+2] = f2bf(v.z); tile[r][cl+3] = f2bf(v.w);
  }
  __syncthreads();
  for (int j = 0; j < 16; ++j) {
    int flat = j * 1024 + t * 4;
    int r = flat >> 7, cl = flat & 127;
    ushort4 o = make_ushort4(tile[cl][r], tile[cl+1][r], tile[cl+2][r], tile[cl+3][r]);
    *(ushort4*)&dst[(size_t)(n0 + r) * 2048 + k0 + cl] = o;
  }
}

// ---------------- GEMM: C[M,N] = A[M,K] * Bt[N,K]^T, 128x128 tile, BK=32 ------
template<int WF32>
__global__ void __launch_bounds__(256) gemm_bt(
    const u16* __restrict__ A, const u16* __restrict__ Bt,
    void* __restrict__ Cp, int ldc, int nbx, int kt_iters, int lda, int ldb)
{
  __shared__ __align__(16) u16 lds_a[4096];
  __shared__ __align__(16) u16 lds_b[4096];
  int nb = gridDim.x;
  int per = nb >> 3;                       // grid % 8 == 0 (XCD swizzle)
  int bid = blockIdx.x;
  int sw = (bid & 7) * per + (bid >> 3);
  int bm = sw / nbx, bn = sw % nbx;
  int tid = threadIdx.x, w = tid >> 6, lane = tid & 63;
  int wy = w >> 1, wx = w & 1, g = lane >> 4, c16 = lane & 15;

  const u16* ga0 = A  + (size_t)(bm * 128 + (2*w+0) * 16 + c16) * lda + g * 8;
  const u16* ga1 = A  + (size_t)(bm * 128 + (2*w+1) * 16 + c16) * lda + g * 8;
  const u16* gb0 = Bt + (size_t)(bn * 128 + (2*w+0) * 16 + c16) * ldb + g * 8;
  const u16* gb1 = Bt + (size_t)(bn * 128 + (2*w+1) * 16 + c16) * ldb + g * 8;
  u16* la0 = &lds_a[(2*w+0) * 512]; u16* la1 = &lds_a[(2*w+1) * 512];
  u16* lb0 = &lds_b[(2*w+0) * 512]; u16* lb1 = &lds_b[(2*w+1) * 512];

  f32x4 acc[4][4];
  const f32x4 vzero = {0.f, 0.f, 0.f, 0.f};
  #pragma unroll
  for (int i = 0; i < 4; ++i)
    #pragma unroll
    for (int j = 0; j < 4; ++j) acc[i][j] = vzero;

  for (int kt = 0; kt < kt_iters; ++kt) {
    int ko = kt * 32;
    __syncthreads();
    GLOAD16(ga0 + ko, la0); GLOAD16(ga1 + ko, la1);
    GLOAD16(gb0 + ko, lb0); GLOAD16(gb1 + ko, lb1);
    __syncthreads();
    bf16x8 af[4], bfv[4];
    #pragma unroll
    for (int f = 0; f < 4; ++f) af[f]  = *(const bf16x8*)&lds_a[(wy*4 + f) * 512 + lane * 8];
    #pragma unroll
    for (int f = 0; f < 4; ++f) bfv[f] = *(const bf16x8*)&lds_b[(wx*4 + f) * 512 + lane * 8];
    #pragma unroll
    for (int i = 0; i < 4; ++i)
      #pragma unroll
      for (int j = 0; j < 4; ++j)
        acc[i][j] = __builtin_amdgcn_mfma_f32_16x16x32_bf16(af[i], bfv[j], acc[i][j], 0, 0, 0);
  }

  #pragma unroll
  for (int i = 0; i < 4; ++i)
    #pragma unroll
    for (int j = 0; j < 4; ++j)
      #pragma unroll
      for (int r = 0; r < 4; ++r) {
        size_t row = (size_t)bm * 128 + wy * 64 + i * 16 + 4 * g + r;
        size_t col = (size_t)bn * 128 + wx * 64 + j * 16 + c16;
        if (WF32) ((float*)Cp)[row * ldc + col] = acc[i][j][r];
        else      ((u16*)Cp)[row * ldc + col]   = f2bf(acc[i][j][r]);
      }
}

// ---------------- RoPE on q columns of C1 in place, pre-scaled ----------------
__global__ void rope_q(u16* __restrict__ C1, const float2* __restrict__ trig) {
  int idx = blockIdx.x * 256 + threadIdx.x;   // 4096 rows * 1024 pairs
  int row = idx >> 10;
  int pi = idx & 1023;
  int h = pi >> 6, i = pi & 63;
  int pos = 1024 + (row & 1023);
  float2 cs = trig[pos * 64 + i];
  u16* p = &C1[(size_t)row * 6144 + h * 128 + 2 * i];
  ushort2 xv = *(const ushort2*)p;
  float x0 = bf2f(xv.x), x1 = bf2f(xv.y);
  const float SC = 0.088388347648318447f * 1.4426950408889634f; // 1/sqrt(128)*log2(e)
  float y0 = (x0 * cs.x - x1 * cs.y) * SC;
  float y1 = (x1 * cs.x + x0 * cs.y) * SC;
  *(ushort2*)p = make_ushort2(f2bf(y0), f2bf(y1));
}

// ---------------- K[bh][s][d] bf16, roped, from past_k | C1 k-cols ------------
__global__ void build_k(const float* __restrict__ past_k, const u16* __restrict__ C1,
                        const float2* __restrict__ trig, u16* __restrict__ Kb) {
  int idx = blockIdx.x * 256 + threadIdx.x;   // 64 * 2048 * 64
  int i = idx & 63;
  int s = (idx >> 6) & 2047;
  int bh = idx >> 17;
  int b = bh >> 4, h = bh & 15;
  float x0, x1;
  if (s < 1024) {
    const float* p = &past_k[(size_t)((b * 1024 + s) * 16 + h) * 128 + 2 * i];
    float2 v = *(const float2*)p;
    x0 = v.x; x1 = v.y;
  } else {
    ushort2 v = *(const ushort2*)&C1[(size_t)(b * 1024 + s - 1024) * 6144 + 2048 + h * 128 + 2 * i];
    x0 = bf2f(v.x); x1 = bf2f(v.y);
  }
  float2 cs = trig[s * 64 + i];
  float y0 = x0 * cs.x - x1 * cs.y;
  float y1 = x1 * cs.x + x0 * cs.y;
  *(ushort2*)&Kb[((size_t)bh * 2048 + s) * 128 + 2 * i] = make_ushort2(f2bf(y0), f2bf(y1));
}

// ---------------- Vt[bh][d][s] bf16 from past_v | C1 v-cols (transpose) -------
__global__ void build_vt(const float* __restrict__ past_v, const u16* __restrict__ C1,
                         u16* __restrict__ Vt) {
  __shared__ u16 tile[128][129];
  int bh = blockIdx.x, st = blockIdx.y;
  int b = bh >> 4, h = bh & 15;
  int s0 = st * 128;
  int t = threadIdx.x;
  for (int j = 0; j < 16; ++j) {
    int flat = j * 1024 + t * 4;
    int sl = flat >> 7, dl = flat & 127;
    u16 a, bq, cq, dq;
    if (st < 8) {
      float4 v = *(const float4*)&past_v[(size_t)((b * 1024 + s0 + sl) * 16 + h) * 128 + dl];
      a = f2bf(v.x); bq = f2bf(v.y); cq = f2bf(v.z); dq = f2bf(v.w);
    } else {
      ushort4 v = *(const ushort4*)&C1[(size_t)(b * 1024 + s0 + sl - 1024) * 6144 + 4096 + h * 128 + dl];
      a = v.x; bq = v.y; cq = v.z; dq = v.w;
    }
    tile[sl][dl] = a; tile[sl][dl+1] = bq; tile[sl][dl+2] = cq; tile[sl][dl+3] = dq;
  }
  __syncthreads();
  for (int j = 0; j < 16; ++j) {
    int flat = j * 1024 + t * 4;
    int dl = flat >> 7, sl = flat & 127;
    ushort4 o = make_ushort4(tile[sl][dl], tile[sl+1][dl], tile[sl+2][dl], tile[sl+3][dl]);
    *(ushort4*)&Vt[((size_t)bh * 128 + dl) * 2048 + s0 + sl] = o;
  }
}

// ---------------- flash attention: QBLK=64, KBLK=64, K/V double-buffered ------
// One __syncthreads per tile; STAGE(t+1) issued BEFORE compute(t) so the
// vmcnt(0) drain at the next barrier only waits for loads that had a full
// tile of compute to land (T3-minimum prefetch recipe).
// Grid: 1D 1024, XCD-chunked: xcd=bid&7 owns bh in [xcd*8, xcd*8+8) so each
// XCD's L2 sees an 8MB K/V working set instead of 64MB; qt descending (tail).
__global__ void __launch_bounds__(256) attn_kernel(
    const u16* __restrict__ Q, const u16* __restrict__ Kb,
    const u16* __restrict__ Vt, u16* __restrict__ Y)
{
  __shared__ __align__(16) u16 ldsK[2][8192];  // 16KB x 2 (dbuf)
  __shared__ __align__(16) u16 ldsV[2][8192];
  __shared__ __align__(16) u16 ldsP[4][1024];  // per-wave 16x64 P, XOR-swizzled
  int bid = blockIdx.x;
  int work = (bid & 7) * 128 + (bid >> 3);     // XCD-contiguous work id
  int bh = work >> 4;
  int qt = 15 - (work & 15);                   // longest blocks first
  int b = bh >> 4, h = bh & 15;
  int w = threadIdx.x >> 6, lane = threadIdx.x & 63;
  int g = lane >> 4, c16 = lane & 15;

  bf16x8 qf[4];
  {
    const u16* qp = Q + (size_t)(b * 1024 + qt * 64 + w * 16 + c16) * 6144 + h * 128 + g * 8;
    #pragma unroll
    for (int c = 0; c < 4; ++c) qf[c] = *(const bf16x8*)(qp + c * 32);
  }
  const u16* Kh = Kb + (size_t)bh * 2048 * 128;
  const u16* Vh = Vt + (size_t)bh * 128 * 2048;
  const u16* gk[4]; const u16* gv[4];
  #pragma unroll
  for (int j = 0; j < 4; ++j) {
    int u = w * 4 + j;
    gk[j] = Kh + (size_t)(16 * w + c16) * 128 + j * 32 + g * 8;
    int dt = u >> 1, sc = u & 1;
    gv[j] = Vh + (size_t)(16 * dt + c16) * 2048 + sc * 32 + g * 8;
  }

  const f32x4 vzero = {0.f, 0.f, 0.f, 0.f};
  f32x4 yacc[8];
  #pragma unroll
  for (int dt = 0; dt < 8; ++dt) yacc[dt] = vzero;
  float m_run[4] = {-3e38f, -3e38f, -3e38f, -3e38f};
  float l_run[4] = {0.f, 0.f, 0.f, 0.f};

  int ntiles = 17 + qt;                        // last tile is the diagonal one

  // prologue: stage tile 0 into buffer 0
  #pragma unroll
  for (int j = 0; j < 4; ++j) GLOAD16(gk[j], &ldsK[0][(w * 4 + j) * 512]);
  #pragma unroll
  for (int j = 0; j < 4; ++j) GLOAD16(gv[j], &ldsV[0][(w * 4 + j) * 512]);

  for (int it = 0; it < ntiles; ++it) {
    int cur = it & 1;
    __syncthreads();                           // drains vmcnt: buf[cur] is ready
    if (it + 1 < ntiles) {                     // prefetch tile it+1 into buf[cur^1]
      int s1 = (it + 1) * 64;
      #pragma unroll
      for (int j = 0; j < 4; ++j) GLOAD16(gk[j] + (size_t)s1 * 128, &ldsK[cur ^ 1][(w * 4 + j) * 512]);
      #pragma unroll
      for (int j = 0; j < 4; ++j) GLOAD16(gv[j] + s1, &ldsV[cur ^ 1][(w * 4 + j) * 512]);
    }
    const u16* kb_l = &ldsK[cur][0];
    const u16* vb_l = &ldsV[cur][0];

    f32x4 sc_[4];
    #pragma unroll
    for (int t = 0; t < 4; ++t) sc_[t] = vzero;
    #pragma unroll
    for (int t = 0; t < 4; ++t)
      #pragma unroll
      for (int c = 0; c < 4; ++c) {
        bf16x8 kbf = *(const bf16x8*)&kb_l[(t * 4 + c) * 512 + lane * 8];
        sc_[t] = __builtin_amdgcn_mfma_f32_16x16x32_bf16(qf[c], kbf, sc_[t], 0, 0, 0);
      }
    if (it == ntiles - 1) {
      #pragma unroll
      for (int t = 0; t < 4; ++t)
        #pragma unroll
        for (int r = 0; r < 4; ++r)
          if (16 * t + c16 > 16 * w + 4 * g + r) sc_[t][r] = -3e38f;
    }

    float tmax[4];
    #pragma unroll
    for (int r = 0; r < 4; ++r)
      tmax[r] = fmaxf(fmaxf(sc_[0][r], sc_[1][r]), fmaxf(sc_[2][r], sc_[3][r]));
    #pragma unroll
    for (int off = 1; off < 16; off <<= 1)
      #pragma unroll
      for (int r = 0; r < 4; ++r) tmax[r] = fmaxf(tmax[r], __shfl_xor(tmax[r], off));

    float m_new[4], alpha[4];
    #pragma unroll
    for (int r = 0; r < 4; ++r) {
      m_new[r] = fmaxf(m_run[r], tmax[r]);
      alpha[r] = exp2f(m_run[r] - m_new[r]);
      m_run[r] = m_new[r];
    }
    float psum[4] = {0.f, 0.f, 0.f, 0.f};
    #pragma unroll
    for (int t = 0; t < 4; ++t)
      #pragma unroll
      for (int r = 0; r < 4; ++r) {
        float p = exp2f(sc_[t][r] - m_new[r]);
        psum[r] += p;
        int row = 4 * g + r, key = 16 * t + c16;
        ldsP[w][row * 64 + (((key >> 3) ^ (row & 7)) << 3) + (key & 7)] = f2bf(p);
      }
    #pragma unroll
    for (int off = 1; off < 16; off <<= 1)
      #pragma unroll
      for (int r = 0; r < 4; ++r) psum[r] += __shfl_xor(psum[r], off);
    #pragma unroll
    for (int r = 0; r < 4; ++r) l_run[r] = l_run[r] * alpha[r] + psum[r];
    #pragma unroll
    for (int dt = 0; dt < 8; ++dt)
      #pragma unroll
      for (int r = 0; r < 4; ++r) yacc[dt][r] *= alpha[r];

    bf16x8 pa[2];
    #pragma unroll
    for (int s2 = 0; s2 < 2; ++s2)
      pa[s2] = *(const bf16x8*)&ldsP[w][c16 * 64 + (((g + 4 * s2) ^ (c16 & 7)) << 3)];

    #pragma unroll
    for (int dt = 0; dt < 8; ++dt)
      #pragma unroll
      for (int s2 = 0; s2 < 2; ++s2) {
        bf16x8 vb = *(const bf16x8*)&vb_l[(dt * 2 + s2) * 512 + lane * 8];
        yacc[dt] = __builtin_amdgcn_mfma_f32_16x16x32_bf16(pa[s2], vb, yacc[dt], 0, 0, 0);
      }
  }

  float linv[4];
  #pragma unroll
  for (int r = 0; r < 4; ++r) linv[r] = 1.0f / l_run[r];
  size_t ybase = (size_t)(b * 1024 + qt * 64 + w * 16) * 2048 + h * 128;
  #pragma unroll
  for (int dt = 0; dt < 8; ++dt)
    #pragma unroll
    for (int r = 0; r < 4; ++r)
      Y[ybase + (size_t)(4 * g + r) * 2048 + dt * 16 + c16] = f2bf(yacc[dt][r] * linv[r]);
}

// ------------------------------------------------------------------------------
extern "C" void kernel_launch(void* const* d_in, const int* in_sizes, int n_in,
                              void* d_out, int out_size, void* d_ws, size_t ws_size,
                              hipStream_t stream) {
  const float* x  = (const float*)d_in[0];
  const float* pk = (const float*)d_in[1];
  const float* pv = (const float*)d_in[2];
  const float* Wq = (const float*)d_in[3];
  const float* Wk = (const float*)d_in[4];
  const float* Wv = (const float*)d_in[5];
  const float* Wo = (const float*)d_in[6];
  float* out = (float*)d_out;
  char* ws = (char*)d_ws;
  size_t off = 0;
  float2* trig = (float2*)(ws + off); off += (size_t)2048 * 64 * 8;
  u16* xbf     = (u16*)(ws + off);    off += (size_t)4096 * 2048 * 2;
  u16* wqkvt   = (u16*)(ws + off);    off += (size_t)6144 * 2048 * 2;
  u16* wot     = (u16*)(ws + off);    off += (size_t)2048 * 2048 * 2;
  u16* c1      = (u16*)(ws + off);    off += (size_t)4096 * 6144 * 2;
  u16* kb      = (u16*)(ws + off);    off += (size_t)64 * 2048 * 128 * 2;
  u16* vt      = (u16*)(ws + off);    off += (size_t)64 * 128 * 2048 * 2;
  u16* yb      = (u16*)(ws + off);    off += (size_t)4096 * 2048 * 2;

  trig_kernel<<<512, 256, 0, stream>>>(trig);
  convert_x<<<8192, 256, 0, stream>>>(x, xbf);
  transpose_w<<<dim3(16, 16), 256, 0, stream>>>(Wq, wqkvt);
  transpose_w<<<dim3(16, 16), 256, 0, stream>>>(Wk, wqkvt + (size_t)2048 * 2048);
  transpose_w<<<dim3(16, 16), 256, 0, stream>>>(Wv, wqkvt + (size_t)2 * 2048 * 2048);
  transpose_w<<<dim3(16, 16), 256, 0, stream>>>(Wo, wot);
  gemm_bt<0><<<1536, 256, 0, stream>>>(xbf, wqkvt, (void*)c1, 6144, 48, 64, 2048, 2048);
  rope_q<<<16384, 256, 0, stream>>>(c1, trig);
  build_k<<<32768, 256, 0, stream>>>(pk, c1, trig, kb);
  build_vt<<<dim3(64, 16), 256, 0, stream>>>(pv, c1, vt);
  attn_kernel<<<1024, 256, 0, stream>>>(c1, kb, vt, yb);
  gemm_bt<1><<<512, 256, 0, stream>>>(yb, wot, (void*)out, 2048, 16, 64, 2048, 2048);
}